// Round 3
// baseline (222.309 us; speedup 1.0000x reference)
//
#include <hip/hip_runtime.h>
#include <hip/hip_bf16.h>

#define BATCH 65536
#define DIN   128
#define DH    512
#define DOUT  128

typedef __attribute__((ext_vector_type(4))) float f32x4;
typedef __attribute__((ext_vector_type(8))) short s16x8;

__device__ __forceinline__ ushort f32_to_bf16_rn(float f) {
    uint32_t u = __float_as_uint(f);
    uint32_t r = (u + 0x7FFFu + ((u >> 16) & 1u)) >> 16;
    return (ushort)r;
}
__device__ __forceinline__ float bf16_to_f32(ushort h) {
    return __uint_as_float(((uint32_t)h) << 16);
}

__device__ __forceinline__ f32x4 mfma16(s16x8 a, s16x8 b, f32x4 c) {
    return __builtin_amdgcn_mfma_f32_16x16x32_bf16(a, b, c, 0, 0, 0);
}

struct Split8 { s16x8 h, l; };
__device__ __forceinline__ Split8 split8(f32x4 v0, f32x4 v1) {
    Split8 s;
#pragma unroll
    for (int j = 0; j < 4; ++j) {
        ushort hh = f32_to_bf16_rn(v0[j]);
        s.h[j] = (short)hh;
        s.l[j] = (short)f32_to_bf16_rn(v0[j] - bf16_to_f32(hh));
    }
#pragma unroll
    for (int j = 0; j < 4; ++j) {
        ushort hh = f32_to_bf16_rn(v1[j]);
        s.h[4 + j] = (short)hh;
        s.l[4 + j] = (short)f32_to_bf16_rn(v1[j] - bf16_to_f32(hh));
    }
    return s;
}

// ---------------------------------------------------------------------------
// prep: block 0 computes decay = softmax(a); blocks 1..64 split B and C into
// bf16 hi/lo in a fragment-linear ("perm") layout so GEMM kernels load
// B-fragments as one coalesced 1KB wave read:
//   perm[(f*64 + lane)*8 + j] = M[k(f,lane,j)][col(f,lane)]
// with k = ks*32 + (lane>>4)*8 + j, col = cg*16 + (lane&15).
// B (K=128,N=512): f = cg*4 + ks   (cg 0..31, ks 0..3)
// C (K=512,N=128): f = cg*16 + ks  (cg 0..7,  ks 0..15)
// ---------------------------------------------------------------------------
__global__ void prep_kernel(const float* __restrict__ a,
                            const float* __restrict__ b,
                            const float* __restrict__ c,
                            float* __restrict__ decay,
                            ushort* __restrict__ bhi, ushort* __restrict__ blo,
                            ushort* __restrict__ chi, ushort* __restrict__ clo)
{
    const int t = threadIdx.x;
    if (blockIdx.x == 0) {
        __shared__ float red[256];
        float v0 = a[t], v1 = a[t + 256];
        red[t] = fmaxf(v0, v1);
        __syncthreads();
        for (int s = 128; s > 0; s >>= 1) {
            if (t < s) red[t] = fmaxf(red[t], red[t + s]);
            __syncthreads();
        }
        float M = red[0];
        __syncthreads();
        float e0 = expf(v0 - M), e1 = expf(v1 - M);
        red[t] = e0 + e1;
        __syncthreads();
        for (int s = 128; s > 0; s >>= 1) {
            if (t < s) red[t] += red[t + s];
            __syncthreads();
        }
        float S = red[0];
        decay[t]       = e0 / S;
        decay[t + 256] = e1 / S;
    } else {
        const int p = (blockIdx.x - 1) * 256 + t;  // 0..16383: (matrix, frag, lane)
        const int mtx = p >> 13;
        const int q = p & 8191;
        const int f = q >> 6;
        const int l = q & 63;
        s16x8 hi, lo;
        if (mtx == 0) {
            const int cg = f >> 2, ks = f & 3;
            const int col = cg * 16 + (l & 15);
            const int kbase = ks * 32 + (l >> 4) * 8;
#pragma unroll
            for (int j = 0; j < 8; ++j) {
                float v = b[(size_t)(kbase + j) * DH + col];
                ushort h = f32_to_bf16_rn(v);
                hi[j] = (short)h;
                lo[j] = (short)f32_to_bf16_rn(v - bf16_to_f32(h));
            }
            *(s16x8*)(bhi + (size_t)q * 8) = hi;
            *(s16x8*)(blo + (size_t)q * 8) = lo;
        } else {
            const int cg = f >> 4, ks = f & 15;
            const int col = cg * 16 + (l & 15);
            const int kbase = ks * 32 + (l >> 4) * 8;
#pragma unroll
            for (int j = 0; j < 8; ++j) {
                float v = c[(size_t)(kbase + j) * DOUT + col];
                ushort h = f32_to_bf16_rn(v);
                hi[j] = (short)h;
                lo[j] = (short)f32_to_bf16_rn(v - bf16_to_f32(h));
            }
            *(s16x8*)(chi + (size_t)q * 8) = hi;
            *(s16x8*)(clo + (size_t)q * 8) = lo;
        }
    }
}

// ---------------------------------------------------------------------------
// k1: xn[64 x 512] tile per block = decay*x + u@b. 256 thr / 4 waves; wave w
// owns cols [w*128, w*128+128): acc 4x8 frags (128 VGPR). U staged f32->hi/lo
// bf16 in XOR-swizzled LDS ([row][k], byte ^= (row&7)<<4 kills the 16-way
// conflict of the 256B row stride). B-frags read straight from L2 (perm).
// ---------------------------------------------------------------------------
__global__ __launch_bounds__(256, 2)
void rnn_k1(const float* __restrict__ u, const float* __restrict__ x,
            const float* __restrict__ decay,
            const ushort* __restrict__ bhi, const ushort* __restrict__ blo,
            float* __restrict__ xn)
{
    __shared__ __align__(16) ushort Ah[64 * 128];
    __shared__ __align__(16) ushort Al[64 * 128];
    const int t = threadIdx.x;
    const int lane = t & 63;
    const int wid = t >> 6;
    const int row0 = blockIdx.x * 64;

    {   // stage U tile [64][128]: lanes 0..15 read 512B contiguous (2 f32x4 each)
        const int kb = t & 15;
        const int rb = t >> 4;
#pragma unroll
        for (int i = 0; i < 4; ++i) {
            const int r = rb + i * 16;
            const float* src = u + (size_t)(row0 + r) * DIN + kb * 8;
            f32x4 v0 = *(const f32x4*)src;
            f32x4 v1 = *(const f32x4*)(src + 4);
            Split8 s = split8(v0, v1);
            const int byte = (r * 256 + kb * 16) ^ ((r & 7) << 4);
            *(s16x8*)((char*)Ah + byte) = s.h;
            *(s16x8*)((char*)Al + byte) = s.l;
        }
    }
    __syncthreads();

    f32x4 acc[4][8];
#pragma unroll
    for (int mf = 0; mf < 4; ++mf)
#pragma unroll
        for (int nf = 0; nf < 8; ++nf)
            acc[mf][nf] = (f32x4){0.f, 0.f, 0.f, 0.f};

#pragma unroll
    for (int ks = 0; ks < 4; ++ks) {
        s16x8 ah[4], al[4];
        const int ko = ks * 32 + (lane >> 4) * 8;
#pragma unroll
        for (int mf = 0; mf < 4; ++mf) {
            const int r = mf * 16 + (lane & 15);
            const int byte = (r * 256 + ko * 2) ^ ((r & 7) << 4);
            ah[mf] = *(const s16x8*)((const char*)Ah + byte);
            al[mf] = *(const s16x8*)((const char*)Al + byte);
        }
#pragma unroll
        for (int nf = 0; nf < 8; ++nf) {
            const int cg = wid * 8 + nf;
            const size_t off = ((size_t)(cg * 4 + ks) * 64 + lane) * 8;
            s16x8 bh = *(const s16x8*)(bhi + off);
            s16x8 bl = *(const s16x8*)(blo + off);
#pragma unroll
            for (int mf = 0; mf < 4; ++mf) acc[mf][nf] = mfma16(ah[mf], bh, acc[mf][nf]);
#pragma unroll
            for (int mf = 0; mf < 4; ++mf) acc[mf][nf] = mfma16(ah[mf], bl, acc[mf][nf]);
#pragma unroll
            for (int mf = 0; mf < 4; ++mf) acc[mf][nf] = mfma16(al[mf], bh, acc[mf][nf]);
        }
    }

    // epilogue: xn = acc + decay[col]*x  (C/D layout: col=lane&15, row=4*(lane>>4)+j)
    const int cl = lane & 15, gq = lane >> 4;
#pragma unroll
    for (int nf = 0; nf < 8; ++nf) {
        const int col = wid * 128 + nf * 16 + cl;
        const float dv = decay[col];
#pragma unroll
        for (int mf = 0; mf < 4; ++mf) {
            const int r = row0 + mf * 16 + gq * 4;
#pragma unroll
            for (int j = 0; j < 4; ++j) {
                const size_t idx = (size_t)(r + j) * DH + col;
                xn[idx] = acc[mf][nf][j] + dv * x[idx];
            }
        }
    }
}

// ---------------------------------------------------------------------------
// k2: out[64 x 128] tile per block = xn @ c, K=512 chunked by 128. Re-stages
// xn f32 from d_out (L2/L3-hot: written by k1 just before) -> split -> LDS.
// Wave w owns cols [w*32, w*32+32): acc 4x2 frags.
// ---------------------------------------------------------------------------
__global__ __launch_bounds__(256, 2)
void rnn_k2(const float* __restrict__ xn,
            const ushort* __restrict__ chi, const ushort* __restrict__ clo,
            float* __restrict__ out)
{
    __shared__ __align__(16) ushort Ah[64 * 128];
    __shared__ __align__(16) ushort Al[64 * 128];
    const int t = threadIdx.x;
    const int lane = t & 63;
    const int wid = t >> 6;
    const int row0 = blockIdx.x * 64;

    f32x4 acc[4][2];
#pragma unroll
    for (int mf = 0; mf < 4; ++mf)
#pragma unroll
        for (int nf = 0; nf < 2; ++nf)
            acc[mf][nf] = (f32x4){0.f, 0.f, 0.f, 0.f};

    for (int kc = 0; kc < 4; ++kc) {
        if (kc) __syncthreads();   // prev iter's LDS reads must finish before overwrite
        {
            const int kb = t & 15;
            const int rb = t >> 4;
#pragma unroll
            for (int i = 0; i < 4; ++i) {
                const int r = rb + i * 16;
                const float* src = xn + (size_t)(row0 + r) * DH + kc * 128 + kb * 8;
                f32x4 v0 = *(const f32x4*)src;
                f32x4 v1 = *(const f32x4*)(src + 4);
                Split8 s = split8(v0, v1);
                const int byte = (r * 256 + kb * 16) ^ ((r & 7) << 4);
                *(s16x8*)((char*)Ah + byte) = s.h;
                *(s16x8*)((char*)Al + byte) = s.l;
            }
        }
        __syncthreads();

#pragma unroll
        for (int ks = 0; ks < 4; ++ks) {
            s16x8 ah[4], al[4];
            const int ko = ks * 32 + (lane >> 4) * 8;
#pragma unroll
            for (int mf = 0; mf < 4; ++mf) {
                const int r = mf * 16 + (lane & 15);
                const int byte = (r * 256 + ko * 2) ^ ((r & 7) << 4);
                ah[mf] = *(const s16x8*)((const char*)Ah + byte);
                al[mf] = *(const s16x8*)((const char*)Al + byte);
            }
            const int ksg = kc * 4 + ks;
#pragma unroll
            for (int nf = 0; nf < 2; ++nf) {
                const int cg = wid * 2 + nf;
                const size_t off = ((size_t)(cg * 16 + ksg) * 64 + lane) * 8;
                s16x8 ch = *(const s16x8*)(chi + off);
                s16x8 cl2 = *(const s16x8*)(clo + off);
#pragma unroll
                for (int mf = 0; mf < 4; ++mf) acc[mf][nf] = mfma16(ah[mf], ch, acc[mf][nf]);
#pragma unroll
                for (int mf = 0; mf < 4; ++mf) acc[mf][nf] = mfma16(ah[mf], cl2, acc[mf][nf]);
#pragma unroll
                for (int mf = 0; mf < 4; ++mf) acc[mf][nf] = mfma16(al[mf], ch, acc[mf][nf]);
            }
        }
    }

    const int cl = lane & 15, gq = lane >> 4;
#pragma unroll
    for (int nf = 0; nf < 2; ++nf) {
        const int col = wid * 32 + nf * 16 + cl;
#pragma unroll
        for (int mf = 0; mf < 4; ++mf) {
            const int r = row0 + mf * 16 + gq * 4;
#pragma unroll
            for (int j = 0; j < 4; ++j)
                out[(size_t)(r + j) * DOUT + col] = acc[mf][nf][j];
        }
    }
}

extern "C" void kernel_launch(void* const* d_in, const int* in_sizes, int n_in,
                              void* d_out, int out_size, void* d_ws, size_t ws_size,
                              hipStream_t stream)
{
    const float* x = (const float*)d_in[0];
    const float* u = (const float*)d_in[1];
    const float* a = (const float*)d_in[2];
    const float* b = (const float*)d_in[3];
    const float* c = (const float*)d_in[4];

    float* xn  = (float*)d_out;                       // [BATCH][DH]
    float* out = xn + (size_t)BATCH * DH;             // [BATCH][DOUT]

    float*  decay = (float*)d_ws;                     // 512 f32
    ushort* bhi = (ushort*)((char*)d_ws + 4096);      // 4 x 128KB perm-split mats
    ushort* blo = bhi + 128 * 512;
    ushort* chi = blo + 128 * 512;
    ushort* clo = chi + 512 * 128;

    prep_kernel<<<dim3(65), dim3(256), 0, stream>>>(a, b, c, decay, bhi, blo, chi, clo);
    rnn_k1<<<dim3(BATCH / 64), dim3(256), 0, stream>>>(u, x, decay, bhi, blo, xn);
    rnn_k2<<<dim3(BATCH / 64), dim3(256), 0, stream>>>(xn, chi, clo, out);
}

// Round 4
// 162.104 us; speedup vs baseline: 1.3714x; 1.3714x over previous
//
#include <hip/hip_runtime.h>
#include <hip/hip_bf16.h>

#define BATCH 65536
#define DIN   128
#define DH    512
#define DOUT  128

typedef __attribute__((ext_vector_type(4))) float f32x4;
typedef __attribute__((ext_vector_type(8))) short s16x8;

__device__ __forceinline__ ushort f32_to_bf16_rn(float f) {
    uint32_t u = __float_as_uint(f);
    uint32_t r = (u + 0x7FFFu + ((u >> 16) & 1u)) >> 16;
    return (ushort)r;
}
__device__ __forceinline__ float bf16_to_f32(ushort h) {
    return __uint_as_float(((uint32_t)h) << 16);
}

__device__ __forceinline__ f32x4 mfma16(s16x8 a, s16x8 b, f32x4 c) {
    return __builtin_amdgcn_mfma_f32_16x16x32_bf16(a, b, c, 0, 0, 0);
}

struct Split8 { s16x8 h, l; };
__device__ __forceinline__ Split8 split8(f32x4 v0, f32x4 v1) {
    Split8 s;
#pragma unroll
    for (int j = 0; j < 4; ++j) {
        ushort hh = f32_to_bf16_rn(v0[j]);
        s.h[j] = (short)hh;
        s.l[j] = (short)f32_to_bf16_rn(v0[j] - bf16_to_f32(hh));
    }
#pragma unroll
    for (int j = 0; j < 4; ++j) {
        ushort hh = f32_to_bf16_rn(v1[j]);
        s.h[4 + j] = (short)hh;
        s.l[4 + j] = (short)f32_to_bf16_rn(v1[j] - bf16_to_f32(hh));
    }
    return s;
}

// ---------------------------------------------------------------------------
// prep: unchanged (verified passing). decay = softmax(a); B,C split to bf16
// hi/lo in fragment-linear layout: perm[(f*64+lane)*8+j] = M[k][col],
// k = ks*32 + (lane>>4)*8 + j, col = cg*16 + (lane&15).
// B: f = cg*4 + ks (cg 0..31); C: f = cg*16 + ks' (cg 0..7, ks' 0..15).
// ---------------------------------------------------------------------------
__global__ void prep_kernel(const float* __restrict__ a,
                            const float* __restrict__ b,
                            const float* __restrict__ c,
                            float* __restrict__ decay,
                            ushort* __restrict__ bhi, ushort* __restrict__ blo,
                            ushort* __restrict__ chi, ushort* __restrict__ clo)
{
    const int t = threadIdx.x;
    if (blockIdx.x == 0) {
        __shared__ float red[256];
        float v0 = a[t], v1 = a[t + 256];
        red[t] = fmaxf(v0, v1);
        __syncthreads();
        for (int s = 128; s > 0; s >>= 1) {
            if (t < s) red[t] = fmaxf(red[t], red[t + s]);
            __syncthreads();
        }
        float M = red[0];
        __syncthreads();
        float e0 = expf(v0 - M), e1 = expf(v1 - M);
        red[t] = e0 + e1;
        __syncthreads();
        for (int s = 128; s > 0; s >>= 1) {
            if (t < s) red[t] += red[t + s];
            __syncthreads();
        }
        float S = red[0];
        decay[t]       = e0 / S;
        decay[t + 256] = e1 / S;
    } else {
        const int p = (blockIdx.x - 1) * 256 + t;
        const int mtx = p >> 13;
        const int q = p & 8191;
        const int f = q >> 6;
        const int l = q & 63;
        s16x8 hi, lo;
        if (mtx == 0) {
            const int cg = f >> 2, ks = f & 3;
            const int col = cg * 16 + (l & 15);
            const int kbase = ks * 32 + (l >> 4) * 8;
#pragma unroll
            for (int j = 0; j < 8; ++j) {
                float v = b[(size_t)(kbase + j) * DH + col];
                ushort h = f32_to_bf16_rn(v);
                hi[j] = (short)h;
                lo[j] = (short)f32_to_bf16_rn(v - bf16_to_f32(h));
            }
            *(s16x8*)(bhi + (size_t)q * 8) = hi;
            *(s16x8*)(blo + (size_t)q * 8) = lo;
        } else {
            const int cg = f >> 4, ks = f & 15;
            const int col = cg * 16 + (l & 15);
            const int kbase = ks * 32 + (l >> 4) * 8;
#pragma unroll
            for (int j = 0; j < 8; ++j) {
                float v = c[(size_t)(kbase + j) * DOUT + col];
                ushort h = f32_to_bf16_rn(v);
                hi[j] = (short)h;
                lo[j] = (short)f32_to_bf16_rn(v - bf16_to_f32(h));
            }
            *(s16x8*)(chi + (size_t)q * 8) = hi;
            *(s16x8*)(clo + (size_t)q * 8) = lo;
        }
    }
}

// ---------------------------------------------------------------------------
// k1 v2: block = 64 rows x 64 cols (grid 1024 x 8). 4 waves (2x2), wave tile
// 32x32, acc 2x2 frags (16 regs). B slice staged to LDS (linear copy of the
// frag-linear ws region, L2-hot) so inner-loop B reads are LDS not global.
// Epilogue transposes acc through LDS -> f32x4-coalesced x/decay/xn.
// LDS 64KB -> 2 blocks/CU; block overlap hides stage+epilogue latency.
// ---------------------------------------------------------------------------
__global__ __launch_bounds__(256, 2)
void rnn_k1(const float* __restrict__ u, const float* __restrict__ x,
            const float* __restrict__ decay,
            const ushort* __restrict__ bhi, const ushort* __restrict__ blo,
            float* __restrict__ xn)
{
    __shared__ __align__(16) char smem[65536];
    ushort* Ah = (ushort*)smem;              // [64][128] bf16, swizzled, 16KB
    ushort* Al = (ushort*)(smem + 16384);    // 16KB
    ushort* Bh = (ushort*)(smem + 32768);    // 16 frags x 1KB
    ushort* Bl = (ushort*)(smem + 49152);

    const int t = threadIdx.x;
    const int lane = t & 63, wid = t >> 6;
    const int row0 = (blockIdx.x >> 3) * 64;
    const int ct   = blockIdx.x & 7;
    const int col0 = ct * 64;

    {   // stage B: 16KB hi + 16KB lo, straight linear copy (coalesced, L2)
        const ushort* srch = bhi + ct * 8192;
        const ushort* srcl = blo + ct * 8192;
#pragma unroll
        for (int p = 0; p < 4; ++p) {
            const int cidx = t + p * 256;
            *(s16x8*)(Bh + cidx * 8) = *(const s16x8*)(srch + cidx * 8);
            *(s16x8*)(Bl + cidx * 8) = *(const s16x8*)(srcl + cidx * 8);
        }
    }
    {   // stage A: u[64][128] f32 -> hi/lo bf16, XOR-swizzled rows
        const int kb = t & 15, rb = t >> 4;
#pragma unroll
        for (int i = 0; i < 4; ++i) {
            const int r = rb + i * 16;
            const float* src = u + (size_t)(row0 + r) * DIN + kb * 8;
            f32x4 v0 = *(const f32x4*)src;
            f32x4 v1 = *(const f32x4*)(src + 4);
            Split8 s = split8(v0, v1);
            const int byte = (r * 256 + kb * 16) ^ ((r & 7) << 4);
            *(s16x8*)((char*)Ah + byte) = s.h;
            *(s16x8*)((char*)Al + byte) = s.l;
        }
    }
    __syncthreads();

    const int wr = wid >> 1, wc = wid & 1;
    const int cl = lane & 15, hk = lane >> 4;

    f32x4 acc[2][2];
#pragma unroll
    for (int mf = 0; mf < 2; ++mf)
#pragma unroll
        for (int nf = 0; nf < 2; ++nf)
            acc[mf][nf] = (f32x4){0.f, 0.f, 0.f, 0.f};

#pragma unroll
    for (int ks = 0; ks < 4; ++ks) {
        const int ko = ks * 32 + hk * 8;
        s16x8 ah[2], al[2];
#pragma unroll
        for (int mf = 0; mf < 2; ++mf) {
            const int r = wr * 32 + mf * 16 + cl;
            const int byte = (r * 256 + ko * 2) ^ ((r & 7) << 4);
            ah[mf] = *(const s16x8*)((const char*)Ah + byte);
            al[mf] = *(const s16x8*)((const char*)Al + byte);
        }
#pragma unroll
        for (int nf = 0; nf < 2; ++nf) {
            const int fl = (wc * 2 + nf) * 4 + ks;
            s16x8 bh = *(const s16x8*)(Bh + fl * 512 + lane * 8);
            s16x8 bl = *(const s16x8*)(Bl + fl * 512 + lane * 8);
#pragma unroll
            for (int mf = 0; mf < 2; ++mf) acc[mf][nf] = mfma16(ah[mf], bh, acc[mf][nf]);
#pragma unroll
            for (int mf = 0; mf < 2; ++mf) acc[mf][nf] = mfma16(ah[mf], bl, acc[mf][nf]);
#pragma unroll
            for (int mf = 0; mf < 2; ++mf) acc[mf][nf] = mfma16(al[mf], bh, acc[mf][nf]);
        }
    }

    // epilogue: acc -> LDS transpose -> coalesced f32x4 combine with decay*x
    __syncthreads();
    float* T = (float*)smem;                 // [64][68] f32 = 17.4KB (A region)
#pragma unroll
    for (int nf = 0; nf < 2; ++nf) {
        const int col = wc * 32 + nf * 16 + cl;
#pragma unroll
        for (int mf = 0; mf < 2; ++mf) {
            const int rb2 = wr * 32 + mf * 16 + hk * 4;
#pragma unroll
            for (int j = 0; j < 4; ++j)
                T[(rb2 + j) * 68 + col] = acc[mf][nf][j];
        }
    }
    __syncthreads();
    {
        const int r = t >> 2, seg = t & 3;
        const size_t gbase = (size_t)(row0 + r) * DH + col0 + seg * 16;
#pragma unroll
        for (int i = 0; i < 4; ++i) {
            f32x4 tv = *(const f32x4*)&T[r * 68 + seg * 16 + i * 4];
            f32x4 xv = *(const f32x4*)&x[gbase + i * 4];
            f32x4 dv = *(const f32x4*)&decay[col0 + seg * 16 + i * 4];
            f32x4 o  = tv + dv * xv;
            *(f32x4*)&xn[gbase + i * 4] = o;
        }
    }
}

// ---------------------------------------------------------------------------
// k2 v2: out[64 x 64] per block (grid 1024 x 2), K=512 in 4 chunks of 128.
// Per chunk: stage xn-chunk (f32->split, L3-hot) + C-chunk frags to LDS,
// compute 48 MFMA/wave. Epilogue LDS-transpose -> coalesced f32x4 stores.
// ---------------------------------------------------------------------------
__global__ __launch_bounds__(256, 2)
void rnn_k2(const float* __restrict__ xn,
            const ushort* __restrict__ chi, const ushort* __restrict__ clo,
            float* __restrict__ out)
{
    __shared__ __align__(16) char smem[65536];
    ushort* Ah = (ushort*)smem;
    ushort* Al = (ushort*)(smem + 16384);
    ushort* Bh = (ushort*)(smem + 32768);
    ushort* Bl = (ushort*)(smem + 49152);

    const int t = threadIdx.x;
    const int lane = t & 63, wid = t >> 6;
    const int row0 = (blockIdx.x >> 1) * 64;
    const int ct   = blockIdx.x & 1;
    const int col0 = ct * 64;
    const int wr = wid >> 1, wc = wid & 1;
    const int cl = lane & 15, hk = lane >> 4;

    f32x4 acc[2][2];
#pragma unroll
    for (int mf = 0; mf < 2; ++mf)
#pragma unroll
        for (int nf = 0; nf < 2; ++nf)
            acc[mf][nf] = (f32x4){0.f, 0.f, 0.f, 0.f};

    for (int kc = 0; kc < 4; ++kc) {
        if (kc) __syncthreads();
        {   // stage C-chunk: 16 frags hi/lo; frag f = cg*16 + kc*4 + ks
#pragma unroll
            for (int p = 0; p < 4; ++p) {
                const int cidx = t + p * 256;          // 16B chunk in [0,1024)
                const int fl = cidx >> 6, e8 = cidx & 63;
                const int f = (ct * 4 + (fl >> 2)) * 16 + kc * 4 + (fl & 3);
                *(s16x8*)(Bh + cidx * 8) = *(const s16x8*)(chi + (size_t)f * 512 + e8 * 8);
                *(s16x8*)(Bl + cidx * 8) = *(const s16x8*)(clo + (size_t)f * 512 + e8 * 8);
            }
        }
        {   // stage A-chunk: xn[64][kc*128 .. +128] f32 -> split
            const int kb = t & 15, rb = t >> 4;
#pragma unroll
            for (int i = 0; i < 4; ++i) {
                const int r = rb + i * 16;
                const float* src = xn + (size_t)(row0 + r) * DH + kc * 128 + kb * 8;
                f32x4 v0 = *(const f32x4*)src;
                f32x4 v1 = *(const f32x4*)(src + 4);
                Split8 s = split8(v0, v1);
                const int byte = (r * 256 + kb * 16) ^ ((r & 7) << 4);
                *(s16x8*)((char*)Ah + byte) = s.h;
                *(s16x8*)((char*)Al + byte) = s.l;
            }
        }
        __syncthreads();

#pragma unroll
        for (int ks = 0; ks < 4; ++ks) {
            const int ko = ks * 32 + hk * 8;
            s16x8 ah[2], al[2];
#pragma unroll
            for (int mf = 0; mf < 2; ++mf) {
                const int r = wr * 32 + mf * 16 + cl;
                const int byte = (r * 256 + ko * 2) ^ ((r & 7) << 4);
                ah[mf] = *(const s16x8*)((const char*)Ah + byte);
                al[mf] = *(const s16x8*)((const char*)Al + byte);
            }
#pragma unroll
            for (int nf = 0; nf < 2; ++nf) {
                const int fl = (wc * 2 + nf) * 4 + ks;
                s16x8 bh = *(const s16x8*)(Bh + fl * 512 + lane * 8);
                s16x8 bl = *(const s16x8*)(Bl + fl * 512 + lane * 8);
#pragma unroll
                for (int mf = 0; mf < 2; ++mf) acc[mf][nf] = mfma16(ah[mf], bh, acc[mf][nf]);
#pragma unroll
                for (int mf = 0; mf < 2; ++mf) acc[mf][nf] = mfma16(ah[mf], bl, acc[mf][nf]);
#pragma unroll
                for (int mf = 0; mf < 2; ++mf) acc[mf][nf] = mfma16(al[mf], bh, acc[mf][nf]);
            }
        }
    }

    __syncthreads();
    float* T = (float*)smem;
#pragma unroll
    for (int nf = 0; nf < 2; ++nf) {
        const int col = wc * 32 + nf * 16 + cl;
#pragma unroll
        for (int mf = 0; mf < 2; ++mf) {
            const int rb2 = wr * 32 + mf * 16 + hk * 4;
#pragma unroll
            for (int j = 0; j < 4; ++j)
                T[(rb2 + j) * 68 + col] = acc[mf][nf][j];
        }
    }
    __syncthreads();
    {
        const int r = t >> 2, seg = t & 3;
        const size_t gbase = (size_t)(row0 + r) * DOUT + col0 + seg * 16;
#pragma unroll
        for (int i = 0; i < 4; ++i)
            *(f32x4*)&out[gbase + i * 4] = *(const f32x4*)&T[r * 68 + seg * 16 + i * 4];
    }
}

extern "C" void kernel_launch(void* const* d_in, const int* in_sizes, int n_in,
                              void* d_out, int out_size, void* d_ws, size_t ws_size,
                              hipStream_t stream)
{
    const float* x = (const float*)d_in[0];
    const float* u = (const float*)d_in[1];
    const float* a = (const float*)d_in[2];
    const float* b = (const float*)d_in[3];
    const float* c = (const float*)d_in[4];

    float* xn  = (float*)d_out;                       // [BATCH][DH]
    float* out = xn + (size_t)BATCH * DH;             // [BATCH][DOUT]

    float*  decay = (float*)d_ws;                     // 512 f32
    ushort* bhi = (ushort*)((char*)d_ws + 4096);      // 4 x 128KB perm-split mats
    ushort* blo = bhi + 128 * 512;
    ushort* chi = blo + 128 * 512;
    ushort* clo = chi + 512 * 128;

    prep_kernel<<<dim3(65), dim3(256), 0, stream>>>(a, b, c, decay, bhi, blo, chi, clo);
    rnn_k1<<<dim3(BATCH / 64 * 8), dim3(256), 0, stream>>>(u, x, decay, bhi, blo, xn);
    rnn_k2<<<dim3(BATCH / 64 * 2), dim3(256), 0, stream>>>(xn, chi, clo, out);
}

// Round 5
// 112.986 us; speedup vs baseline: 1.9676x; 1.4347x over previous
//
#include <hip/hip_runtime.h>
#include <hip/hip_bf16.h>

#define BATCH 65536
#define DIN   128
#define DH    512
#define DOUT  128
#define ROWS  32

typedef __attribute__((ext_vector_type(4))) float f32x4;
typedef __attribute__((ext_vector_type(8))) short s16x8;

__device__ __forceinline__ ushort f32_to_bf16_rn(float f) {
    uint32_t u = __float_as_uint(f);
    uint32_t r = (u + 0x7FFFu + ((u >> 16) & 1u)) >> 16;
    return (ushort)r;
}
__device__ __forceinline__ float bf16_to_f32(ushort h) {
    return __uint_as_float(((uint32_t)h) << 16);
}

__device__ __forceinline__ f32x4 mfma16(s16x8 a, s16x8 b, f32x4 c) {
    return __builtin_amdgcn_mfma_f32_16x16x32_bf16(a, b, c, 0, 0, 0);
}

struct Split8 { s16x8 h, l; };
__device__ __forceinline__ Split8 split8(f32x4 v0, f32x4 v1) {
    Split8 s;
#pragma unroll
    for (int j = 0; j < 4; ++j) {
        ushort hh = f32_to_bf16_rn(v0[j]);
        s.h[j] = (short)hh;
        s.l[j] = (short)f32_to_bf16_rn(v0[j] - bf16_to_f32(hh));
    }
#pragma unroll
    for (int j = 0; j < 4; ++j) {
        ushort hh = f32_to_bf16_rn(v1[j]);
        s.h[4 + j] = (short)hh;
        s.l[4 + j] = (short)f32_to_bf16_rn(v1[j] - bf16_to_f32(hh));
    }
    return s;
}

// ---------------------------------------------------------------------------
// prep: unchanged (verified passing twice). decay = softmax(a); B,C split to
// bf16 hi/lo fragment-linear: perm[(f*64+lane)*8+j] = M[k][col],
// k = ks*32 + (lane>>4)*8 + j, col = cg*16 + (lane&15).
// B: f = cg*4 + ks (cg 0..31); C: f = cg*16 + ksg (cg 0..7, ksg 0..15).
// ---------------------------------------------------------------------------
__global__ void prep_kernel(const float* __restrict__ a,
                            const float* __restrict__ b,
                            const float* __restrict__ c,
                            float* __restrict__ decay,
                            ushort* __restrict__ bhi, ushort* __restrict__ blo,
                            ushort* __restrict__ chi, ushort* __restrict__ clo)
{
    const int t = threadIdx.x;
    if (blockIdx.x == 0) {
        __shared__ float red[256];
        float v0 = a[t], v1 = a[t + 256];
        red[t] = fmaxf(v0, v1);
        __syncthreads();
        for (int s = 128; s > 0; s >>= 1) {
            if (t < s) red[t] = fmaxf(red[t], red[t + s]);
            __syncthreads();
        }
        float M = red[0];
        __syncthreads();
        float e0 = expf(v0 - M), e1 = expf(v1 - M);
        red[t] = e0 + e1;
        __syncthreads();
        for (int s = 128; s > 0; s >>= 1) {
            if (t < s) red[t] += red[t + s];
            __syncthreads();
        }
        float S = red[0];
        decay[t]       = e0 / S;
        decay[t + 256] = e1 / S;
    } else {
        const int p = (blockIdx.x - 1) * 256 + t;
        const int mtx = p >> 13;
        const int q = p & 8191;
        const int f = q >> 6;
        const int l = q & 63;
        s16x8 hi, lo;
        if (mtx == 0) {
            const int cg = f >> 2, ks = f & 3;
            const int col = cg * 16 + (l & 15);
            const int kbase = ks * 32 + (l >> 4) * 8;
#pragma unroll
            for (int j = 0; j < 8; ++j) {
                float v = b[(size_t)(kbase + j) * DH + col];
                ushort h = f32_to_bf16_rn(v);
                hi[j] = (short)h;
                lo[j] = (short)f32_to_bf16_rn(v - bf16_to_f32(h));
            }
            *(s16x8*)(bhi + (size_t)q * 8) = hi;
            *(s16x8*)(blo + (size_t)q * 8) = lo;
        } else {
            const int cg = f >> 4, ks = f & 15;
            const int col = cg * 16 + (l & 15);
            const int kbase = ks * 32 + (l >> 4) * 8;
#pragma unroll
            for (int j = 0; j < 8; ++j) {
                float v = c[(size_t)(kbase + j) * DOUT + col];
                ushort h = f32_to_bf16_rn(v);
                hi[j] = (short)h;
                lo[j] = (short)f32_to_bf16_rn(v - bf16_to_f32(h));
            }
            *(s16x8*)(chi + (size_t)q * 8) = hi;
            *(s16x8*)(clo + (size_t)q * 8) = lo;
        }
    }
}

// ---------------------------------------------------------------------------
// fused: block = 32 batch rows (grid 2048). 4 waves. LDS 24KB -> 5-6 blk/CU.
// Stage u-split once. Per ct chunk (64 cols of DH):
//   GEMM1: wave wc computes xn-chunk cols [ct*64+wc*16, +16), K=128.
//          B-frags read from L2 (frag-linear ws). x prefetched to regs first.
//   epilogue: v = acc + decay*x; store xn; split v -> Xh/Xl LDS (swizzled).
//   GEMM2: out[32x128] += X @ C-chunk (K=64). C-frags from L2. acc persists.
// Final: store out. Barriers: 2 per chunk (X WAR + X visibility).
// ---------------------------------------------------------------------------
__global__ __launch_bounds__(256, 4)
void rnn_fused(const float* __restrict__ u, const float* __restrict__ x,
               const float* __restrict__ decay,
               const ushort* __restrict__ bhi, const ushort* __restrict__ blo,
               const ushort* __restrict__ chi, const ushort* __restrict__ clo,
               float* __restrict__ xn, float* __restrict__ out)
{
    __shared__ __align__(16) char smem[24576];
    ushort* Ah = (ushort*)smem;             // [32][128] bf16 hi, swz, 8KB
    ushort* Al = (ushort*)(smem + 8192);    // 8KB
    ushort* Xh = (ushort*)(smem + 16384);   // [32][64] bf16 hi, swz, 4KB
    ushort* Xl = (ushort*)(smem + 20480);   // 4KB

    const int t = threadIdx.x;
    const int lane = t & 63, wc = t >> 6;
    const int cl = lane & 15, hk = lane >> 4;
    const int row0 = blockIdx.x * ROWS;

    {   // stage A: u[32][128] f32 -> hi/lo bf16 swizzled; 64B/thread coalesced
        const int r = t >> 3;
        const int kb = (t & 7) * 2;
#pragma unroll
        for (int i = 0; i < 2; ++i) {
            const float* src = u + (size_t)(row0 + r) * DIN + (kb + i) * 8;
            f32x4 v0 = *(const f32x4*)src;
            f32x4 v1 = *(const f32x4*)(src + 4);
            Split8 s = split8(v0, v1);
            const int byte = (r * 256 + (kb + i) * 16) ^ ((r & 7) << 4);
            *(s16x8*)((char*)Ah + byte) = s.h;
            *(s16x8*)((char*)Al + byte) = s.l;
        }
    }
    __syncthreads();

    f32x4 acc2[2][2];
#pragma unroll
    for (int mf = 0; mf < 2; ++mf)
#pragma unroll
        for (int nf = 0; nf < 2; ++nf)
            acc2[mf][nf] = (f32x4){0.f, 0.f, 0.f, 0.f};

    for (int ct = 0; ct < 8; ++ct) {
        // ---- prefetch x + decay for this chunk (latency hides under GEMM1)
        const int col = ct * 64 + wc * 16 + cl;
        const float dv = decay[col];
        float xv[2][4];
#pragma unroll
        for (int mf = 0; mf < 2; ++mf)
#pragma unroll
            for (int j = 0; j < 4; ++j)
                xv[mf][j] = x[(size_t)(row0 + mf * 16 + hk * 4 + j) * DH + col];

        // ---- GEMM1: acc1 = u @ B chunk; wave tile 32 rows x 16 cols
        f32x4 acc1[2];
        acc1[0] = (f32x4){0.f, 0.f, 0.f, 0.f};
        acc1[1] = (f32x4){0.f, 0.f, 0.f, 0.f};
#pragma unroll
        for (int ks = 0; ks < 4; ++ks) {
            const int ko = ks * 32 + hk * 8;
            s16x8 ah[2], al[2];
#pragma unroll
            for (int mf = 0; mf < 2; ++mf) {
                const int r = mf * 16 + cl;
                const int byte = (r * 256 + ko * 2) ^ ((r & 7) << 4);
                ah[mf] = *(const s16x8*)((const char*)Ah + byte);
                al[mf] = *(const s16x8*)((const char*)Al + byte);
            }
            const size_t fB = (size_t)((ct * 4 + wc) * 4 + ks) * 512 + lane * 8;
            s16x8 bh = *(const s16x8*)(bhi + fB);
            s16x8 bl = *(const s16x8*)(blo + fB);
#pragma unroll
            for (int mf = 0; mf < 2; ++mf) acc1[mf] = mfma16(ah[mf], bh, acc1[mf]);
#pragma unroll
            for (int mf = 0; mf < 2; ++mf) acc1[mf] = mfma16(ah[mf], bl, acc1[mf]);
#pragma unroll
            for (int mf = 0; mf < 2; ++mf) acc1[mf] = mfma16(al[mf], bh, acc1[mf]);
        }

        __syncthreads();   // prev chunk's GEMM2 X-reads complete (WAR)

        // ---- epilogue: xn = acc1 + decay*x; also split into X LDS
#pragma unroll
        for (int mf = 0; mf < 2; ++mf) {
#pragma unroll
            for (int j = 0; j < 4; ++j) {
                const int rl = mf * 16 + hk * 4 + j;
                const float v = acc1[mf][j] + dv * xv[mf][j];
                xn[(size_t)(row0 + rl) * DH + col] = v;
                const ushort hh = f32_to_bf16_rn(v);
                const ushort ll = f32_to_bf16_rn(v - bf16_to_f32(hh));
                const int cbyte = (rl * 128 + (wc * 16 + cl) * 2) ^ ((rl & 7) << 4);
                *(ushort*)((char*)Xh + cbyte) = hh;
                *(ushort*)((char*)Xl + cbyte) = ll;
            }
        }
        __syncthreads();   // X visible to all waves

        // ---- GEMM2: out += X @ C-chunk; wave tile 32 rows x 32 cols, K=64
#pragma unroll
        for (int ks2 = 0; ks2 < 2; ++ks2) {
            const int ko = ks2 * 32 + hk * 8;
            s16x8 ah2[2], al2[2];
#pragma unroll
            for (int mf = 0; mf < 2; ++mf) {
                const int r = mf * 16 + cl;
                const int byte = (r * 128 + ko * 2) ^ ((r & 7) << 4);
                ah2[mf] = *(const s16x8*)((const char*)Xh + byte);
                al2[mf] = *(const s16x8*)((const char*)Xl + byte);
            }
#pragma unroll
            for (int nf = 0; nf < 2; ++nf) {
                const size_t fC = (size_t)((wc * 2 + nf) * 16 + ct * 2 + ks2) * 512 + lane * 8;
                s16x8 ch = *(const s16x8*)(chi + fC);
                s16x8 cc = *(const s16x8*)(clo + fC);
#pragma unroll
                for (int mf = 0; mf < 2; ++mf) acc2[mf][nf] = mfma16(ah2[mf], ch, acc2[mf][nf]);
#pragma unroll
                for (int mf = 0; mf < 2; ++mf) acc2[mf][nf] = mfma16(ah2[mf], cc, acc2[mf][nf]);
#pragma unroll
                for (int mf = 0; mf < 2; ++mf) acc2[mf][nf] = mfma16(al2[mf], ch, acc2[mf][nf]);
            }
        }
    }

    // ---- final: store out[32 x 128]; wave covers cols [wc*32, +32)
#pragma unroll
    for (int nf = 0; nf < 2; ++nf) {
        const int ocol = wc * 32 + nf * 16 + cl;
#pragma unroll
        for (int mf = 0; mf < 2; ++mf) {
#pragma unroll
            for (int j = 0; j < 4; ++j) {
                const int rl = mf * 16 + hk * 4 + j;
                out[(size_t)(row0 + rl) * DOUT + ocol] = acc2[mf][nf][j];
            }
        }
    }
}

extern "C" void kernel_launch(void* const* d_in, const int* in_sizes, int n_in,
                              void* d_out, int out_size, void* d_ws, size_t ws_size,
                              hipStream_t stream)
{
    const float* x = (const float*)d_in[0];
    const float* u = (const float*)d_in[1];
    const float* a = (const float*)d_in[2];
    const float* b = (const float*)d_in[3];
    const float* c = (const float*)d_in[4];

    float* xn  = (float*)d_out;                       // [BATCH][DH]
    float* out = xn + (size_t)BATCH * DH;             // [BATCH][DOUT]

    float*  decay = (float*)d_ws;                     // 512 f32
    ushort* bhi = (ushort*)((char*)d_ws + 4096);      // 4 x 128KB perm-split mats
    ushort* blo = bhi + 128 * 512;
    ushort* chi = blo + 128 * 512;
    ushort* clo = chi + 512 * 128;

    prep_kernel<<<dim3(65), dim3(256), 0, stream>>>(a, b, c, decay, bhi, blo, chi, clo);
    rnn_fused<<<dim3(BATCH / ROWS), dim3(256), 0, stream>>>(u, x, decay, bhi, blo, chi, clo, xn, out);
}